// Round 1
// baseline (4830.720 us; speedup 1.0000x reference)
//
#include <hip/hip_runtime.h>

#define NN 100000
#define EE 1600000
#define HIDD 128
#define TGTT 64
#define GGG 512

// ---- per-graph offsets: goff[g] = first node index with batch >= g (batch is sorted)
__global__ void k_goff(const int* __restrict__ batch, int* __restrict__ goff) {
    int t = blockIdx.x * blockDim.x + threadIdx.x;
    if (t > GGG) return;
    int lo = 0, hi = NN;
    while (lo < hi) { int mid = (lo + hi) >> 1; if (batch[mid] < t) lo = mid + 1; else hi = mid; }
    goff[t] = lo;
}

// ---- edge aggregation: A[dst] += h[src], one (edge, float2) per thread
__global__ __launch_bounds__(256) void k_aggr(const float* __restrict__ hin,
                                              const int* __restrict__ ei,
                                              float* __restrict__ A) {
    long tid = (long)blockIdx.x * 256 + threadIdx.x;
    long e = tid >> 6;
    if (e >= EE) return;
    int f2 = (int)(tid & 63);
    int s = ei[e];
    int d = ei[EE + e];
    float2 v = ((const float2*)(hin + (long)s * HIDD))[f2];
    float* dst = A + (long)d * HIDD + f2 * 2;
    atomicAdd(dst, v.x);
    atomicAdd(dst + 1, v.y);
}

// ---- u = (1+eps)*h + aggr  (in-place into A)
__global__ __launch_bounds__(256) void k_u(const float* __restrict__ hin,
                                           float* __restrict__ A,
                                           const float* __restrict__ eps, int l) {
    int i = blockIdx.x * 256 + threadIdx.x;
    if (i >= NN * (HIDD / 4)) return;
    float e1 = 1.0f + eps[l];
    float4 h = ((const float4*)hin)[i];
    float4 a = ((float4*)A)[i];
    a.x = e1 * h.x + a.x; a.y = e1 * h.y + a.y;
    a.z = e1 * h.z + a.z; a.w = e1 * h.w + a.w;
    ((float4*)A)[i] = a;
}

// ---- fused 2-layer MLP: Y = relu(X@W1+B1)@W2+B2, 32-node tile per block
__global__ __launch_bounds__(256) void k_mlp2(const float* __restrict__ X,
                                              const float* __restrict__ W1, const float* __restrict__ B1,
                                              const float* __restrict__ W2, const float* __restrict__ B2,
                                              float* __restrict__ Y) {
    __shared__ float sX[32 * HIDD];
    __shared__ float sT[32 * HIDD];
    int tid = threadIdx.x;
    long base = (long)blockIdx.x * 32;
    const float4* Xv = (const float4*)(X + base * HIDD);
    float4* sXv = (float4*)sX;
#pragma unroll
    for (int i = 0; i < 4; i++) sXv[tid + 256 * i] = Xv[tid + 256 * i];
    __syncthreads();
    const int fb = (tid & 31) * 4;
    const int nb = (tid >> 5) * 4;
    float acc[4][4];
#pragma unroll
    for (int j = 0; j < 4; j++) { float b = B1[fb + j]; acc[0][j] = b; acc[1][j] = b; acc[2][j] = b; acc[3][j] = b; }
#pragma unroll 4
    for (int k = 0; k < HIDD; k++) {
        float4 w = *(const float4*)(W1 + k * HIDD + fb);
        float a0 = sX[(nb + 0) * HIDD + k], a1 = sX[(nb + 1) * HIDD + k];
        float a2 = sX[(nb + 2) * HIDD + k], a3 = sX[(nb + 3) * HIDD + k];
        acc[0][0] += a0 * w.x; acc[0][1] += a0 * w.y; acc[0][2] += a0 * w.z; acc[0][3] += a0 * w.w;
        acc[1][0] += a1 * w.x; acc[1][1] += a1 * w.y; acc[1][2] += a1 * w.z; acc[1][3] += a1 * w.w;
        acc[2][0] += a2 * w.x; acc[2][1] += a2 * w.y; acc[2][2] += a2 * w.z; acc[2][3] += a2 * w.w;
        acc[3][0] += a3 * w.x; acc[3][1] += a3 * w.y; acc[3][2] += a3 * w.z; acc[3][3] += a3 * w.w;
    }
#pragma unroll
    for (int i = 0; i < 4; i++) {
        float4 v;
        v.x = fmaxf(acc[i][0], 0.f); v.y = fmaxf(acc[i][1], 0.f);
        v.z = fmaxf(acc[i][2], 0.f); v.w = fmaxf(acc[i][3], 0.f);
        *(float4*)(sT + (nb + i) * HIDD + fb) = v;
    }
    __syncthreads();
#pragma unroll
    for (int j = 0; j < 4; j++) { float b = B2[fb + j]; acc[0][j] = b; acc[1][j] = b; acc[2][j] = b; acc[3][j] = b; }
#pragma unroll 4
    for (int k = 0; k < HIDD; k++) {
        float4 w = *(const float4*)(W2 + k * HIDD + fb);
        float a0 = sT[(nb + 0) * HIDD + k], a1 = sT[(nb + 1) * HIDD + k];
        float a2 = sT[(nb + 2) * HIDD + k], a3 = sT[(nb + 3) * HIDD + k];
        acc[0][0] += a0 * w.x; acc[0][1] += a0 * w.y; acc[0][2] += a0 * w.z; acc[0][3] += a0 * w.w;
        acc[1][0] += a1 * w.x; acc[1][1] += a1 * w.y; acc[1][2] += a1 * w.z; acc[1][3] += a1 * w.w;
        acc[2][0] += a2 * w.x; acc[2][1] += a2 * w.y; acc[2][2] += a2 * w.z; acc[2][3] += a2 * w.w;
        acc[3][0] += a3 * w.x; acc[3][1] += a3 * w.y; acc[3][2] += a3 * w.z; acc[3][3] += a3 * w.w;
    }
#pragma unroll
    for (int i = 0; i < 4; i++) {
        float4 v; v.x = acc[i][0]; v.y = acc[i][1]; v.z = acc[i][2]; v.w = acc[i][3];
        *(float4*)(Y + (base + nb + i) * HIDD + fb) = v;
    }
}

// ---- single GEMM + relu: Y = relu(X@W+B), same tile structure
__global__ __launch_bounds__(256) void k_gemm_relu(const float* __restrict__ X,
                                                   const float* __restrict__ W, const float* __restrict__ B,
                                                   float* __restrict__ Y) {
    __shared__ float sX[32 * HIDD];
    int tid = threadIdx.x;
    long base = (long)blockIdx.x * 32;
    const float4* Xv = (const float4*)(X + base * HIDD);
    float4* sXv = (float4*)sX;
#pragma unroll
    for (int i = 0; i < 4; i++) sXv[tid + 256 * i] = Xv[tid + 256 * i];
    __syncthreads();
    const int fb = (tid & 31) * 4;
    const int nb = (tid >> 5) * 4;
    float acc[4][4];
#pragma unroll
    for (int j = 0; j < 4; j++) { float b = B[fb + j]; acc[0][j] = b; acc[1][j] = b; acc[2][j] = b; acc[3][j] = b; }
#pragma unroll 4
    for (int k = 0; k < HIDD; k++) {
        float4 w = *(const float4*)(W + k * HIDD + fb);
        float a0 = sX[(nb + 0) * HIDD + k], a1 = sX[(nb + 1) * HIDD + k];
        float a2 = sX[(nb + 2) * HIDD + k], a3 = sX[(nb + 3) * HIDD + k];
        acc[0][0] += a0 * w.x; acc[0][1] += a0 * w.y; acc[0][2] += a0 * w.z; acc[0][3] += a0 * w.w;
        acc[1][0] += a1 * w.x; acc[1][1] += a1 * w.y; acc[1][2] += a1 * w.z; acc[1][3] += a1 * w.w;
        acc[2][0] += a2 * w.x; acc[2][1] += a2 * w.y; acc[2][2] += a2 * w.z; acc[2][3] += a2 * w.w;
        acc[3][0] += a3 * w.x; acc[3][1] += a3 * w.y; acc[3][2] += a3 * w.z; acc[3][3] += a3 * w.w;
    }
#pragma unroll
    for (int i = 0; i < 4; i++) {
        float4 v;
        v.x = fmaxf(acc[i][0], 0.f); v.y = fmaxf(acc[i][1], 0.f);
        v.z = fmaxf(acc[i][2], 0.f); v.w = fmaxf(acc[i][3], 0.f);
        *(float4*)(Y + (base + nb + i) * HIDD + fb) = v;
    }
}

// ---- GraphNorm + relu, in-place; one block (512 thr = 4 node-lanes x 128 feats) per graph
__global__ __launch_bounds__(512) void k_gnorm(float* __restrict__ H, const int* __restrict__ goff,
                                               const float* __restrict__ scale,
                                               const float* __restrict__ weight,
                                               const float* __restrict__ bias) {
    int g = blockIdx.x;
    int s = goff[g], e = goff[g + 1];
    float cnt = (float)max(e - s, 1);
    int f = threadIdx.x & 127;
    int r = threadIdx.x >> 7;
    float sum = 0.f, sumsq = 0.f;
    for (int i = s + r; i < e; i += 4) {
        float v = H[(long)i * HIDD + f];
        sum += v; sumsq += v * v;
    }
    __shared__ float red[2][4][128];
    red[0][r][f] = sum; red[1][r][f] = sumsq;
    __syncthreads();
    if (r == 0) {
        sum = red[0][0][f] + red[0][1][f] + red[0][2][f] + red[0][3][f];
        sumsq = red[1][0][f] + red[1][1][f] + red[1][2][f] + red[1][3][f];
        float mean = sum / cnt;
        float ms = mean * scale[f];
        float var = sumsq / cnt - 2.f * ms * mean + ms * ms;
        float inv = weight[f] / sqrtf(var + 1e-8f);
        red[0][0][f] = ms; red[1][0][f] = inv;
    }
    __syncthreads();
    float ms = red[0][0][f], inv = red[1][0][f];
    float b = bias[f];
    for (int i = s + r; i < e; i += 4) {
        long idx = (long)i * HIDD + f;
        float v = (H[idx] - ms) * inv + b;
        H[idx] = v > 0.f ? v : 0.f;
    }
}

// ---- per-graph pooling of z1 [N,128] -> pooled [G,128]
__global__ __launch_bounds__(512) void k_pool(const float* __restrict__ Z, const int* __restrict__ goff,
                                              float* __restrict__ pooled) {
    int g = blockIdx.x;
    int s = goff[g], e = goff[g + 1];
    int f = threadIdx.x & 127;
    int r = threadIdx.x >> 7;
    float sum = 0.f;
    for (int i = s + r; i < e; i += 4) sum += Z[(long)i * HIDD + f];
    __shared__ float red[4][128];
    red[r][f] = sum;
    __syncthreads();
    if (r == 0) pooled[g * HIDD + f] = red[0][f] + red[1][f] + red[2][f] + red[3][f];
}

// ---- out[g, l*64+t] = pooled[g] @ pw2 + count*pb2
__global__ __launch_bounds__(64) void k_out(const float* __restrict__ pooled, const int* __restrict__ goff,
                                            const float* __restrict__ W, const float* __restrict__ B,
                                            float* __restrict__ out, int l) {
    int g = blockIdx.x;
    int t = threadIdx.x;
    __shared__ float p[128];
    p[t] = pooled[g * HIDD + t];
    p[t + 64] = pooled[g * HIDD + 64 + t];
    __syncthreads();
    float cnt = (float)(goff[g + 1] - goff[g]);
    float acc = cnt * B[t];
    for (int k = 0; k < HIDD; k++) acc += p[k] * W[k * TGTT + t];
    out[(long)g * (3 * TGTT) + l * TGTT + t] = acc;
}

extern "C" void kernel_launch(void* const* d_in, const int* in_sizes, int n_in,
                              void* d_out, int out_size, void* d_ws, size_t ws_size,
                              hipStream_t stream) {
    const float* x    = (const float*)d_in[0];
    const int*   ei   = (const int*)d_in[1];
    const int*   batch= (const int*)d_in[2];
    const float* cw1  = (const float*)d_in[3];
    const float* cb1  = (const float*)d_in[4];
    const float* cw2  = (const float*)d_in[5];
    const float* cb2  = (const float*)d_in[6];
    const float* eps  = (const float*)d_in[7];
    const float* gsc  = (const float*)d_in[8];
    const float* gw   = (const float*)d_in[9];
    const float* gb   = (const float*)d_in[10];
    const float* pw1  = (const float*)d_in[11];
    const float* pb1  = (const float*)d_in[12];
    const float* pw2  = (const float*)d_in[13];
    const float* pb2  = (const float*)d_in[14];
    float* out = (float*)d_out;

    float* H      = (float*)d_ws;                      // N*128
    float* A      = H + (size_t)NN * HIDD;             // N*128
    float* pooled = A + (size_t)NN * HIDD;             // G*128
    int*   goff   = (int*)(pooled + (size_t)GGG * HIDD); // G+1

    k_goff<<<3, 256, 0, stream>>>(batch, goff);

    for (int l = 0; l < 3; l++) {
        const float* hin = (l == 0) ? x : H;
        hipMemsetAsync(A, 0, (size_t)NN * HIDD * sizeof(float), stream);
        long aggr_threads = (long)EE * 64;
        k_aggr<<<(int)((aggr_threads + 255) / 256), 256, 0, stream>>>(hin, ei, A);
        k_u<<<(NN * (HIDD / 4) + 255) / 256, 256, 0, stream>>>(hin, A, eps, l);
        k_mlp2<<<NN / 32, 256, 0, stream>>>(A, cw1 + (size_t)l * HIDD * HIDD, cb1 + l * HIDD,
                                            cw2 + (size_t)l * HIDD * HIDD, cb2 + l * HIDD, H);
        k_gnorm<<<GGG, 512, 0, stream>>>(H, goff, gsc + l * HIDD, gw + l * HIDD, gb + l * HIDD);
        k_gemm_relu<<<NN / 32, 256, 0, stream>>>(H, pw1 + (size_t)l * HIDD * HIDD, pb1 + l * HIDD, A);
        k_pool<<<GGG, 512, 0, stream>>>(A, goff, pooled);
        k_out<<<GGG, 64, 0, stream>>>(pooled, goff, pw2 + (size_t)l * HIDD * TGTT, pb2 + l * TGTT, out, l);
    }
}

// Round 2
// 1373.531 us; speedup vs baseline: 3.5170x; 3.5170x over previous
//
#include <hip/hip_runtime.h>

#define NN 100000
#define EE 1600000
#define HIDD 128
#define TGTT 64
#define GGG 512
#define SCANB 1024
#define NSB ((NN + SCANB - 1) / SCANB)   // 98 scan blocks

// ---- per-graph offsets: goff[g] = first node index with batch >= g (batch is sorted)
__global__ void k_goff(const int* __restrict__ batch, int* __restrict__ goff) {
    int t = blockIdx.x * blockDim.x + threadIdx.x;
    if (t > GGG) return;
    int lo = 0, hi = NN;
    while (lo < hi) { int mid = (lo + hi) >> 1; if (batch[mid] < t) lo = mid + 1; else hi = mid; }
    goff[t] = lo;
}

// ======================= CSR build (once per call) =======================
__global__ __launch_bounds__(256) void k_count(const int* __restrict__ ei, int* __restrict__ deg) {
    int e = blockIdx.x * 256 + threadIdx.x;
    if (e >= EE) return;
    atomicAdd(&deg[ei[EE + e]], 1);
}

__global__ __launch_bounds__(SCANB) void k_bsum(const int* __restrict__ deg, int* __restrict__ bsum) {
    __shared__ int sd[SCANB];
    int i = blockIdx.x * SCANB + threadIdx.x;
    sd[threadIdx.x] = (i < NN) ? deg[i] : 0;
    __syncthreads();
    for (int off = SCANB / 2; off > 0; off >>= 1) {
        if (threadIdx.x < off) sd[threadIdx.x] += sd[threadIdx.x + off];
        __syncthreads();
    }
    if (threadIdx.x == 0) bsum[blockIdx.x] = sd[0];
}

__global__ void k_bscan(int* __restrict__ bsum, int* __restrict__ rowptr) {
    if (threadIdx.x == 0) {
        int acc = 0;
        for (int b = 0; b < NSB; b++) { int v = bsum[b]; bsum[b] = acc; acc += v; }
        rowptr[NN] = acc;   // == EE
    }
}

__global__ __launch_bounds__(SCANB) void k_scan(const int* __restrict__ deg, const int* __restrict__ bsum,
                                                int* __restrict__ rowptr) {
    __shared__ int sd[SCANB];
    int i = blockIdx.x * SCANB + threadIdx.x;
    int v = (i < NN) ? deg[i] : 0;
    sd[threadIdx.x] = v;
    __syncthreads();
    for (int off = 1; off < SCANB; off <<= 1) {
        int t = (threadIdx.x >= off) ? sd[threadIdx.x - off] : 0;
        __syncthreads();
        sd[threadIdx.x] += t;
        __syncthreads();
    }
    if (i < NN) rowptr[i] = bsum[blockIdx.x] + sd[threadIdx.x] - v;  // exclusive
}

__global__ __launch_bounds__(256) void k_fill(const int* __restrict__ ei, const int* __restrict__ rowptr,
                                              int* __restrict__ cursor, int* __restrict__ csr) {
    int e = blockIdx.x * 256 + threadIdx.x;
    if (e >= EE) return;
    int s = ei[e], d = ei[EE + e];
    int pos = rowptr[d] + atomicAdd(&cursor[d], 1);
    csr[pos] = s;
}

// ======================= fused gather: A[i] = (1+eps)*h[i] + sum_j h[csr[j]] =======================
// 32 lanes per node (each lane owns a float4), 8 nodes per 256-thread block.
__global__ __launch_bounds__(256) void k_gather(const float* __restrict__ hin,
                                                const int* __restrict__ rowptr,
                                                const int* __restrict__ csr,
                                                const float* __restrict__ eps, int l,
                                                float* __restrict__ A) {
    int node = blockIdx.x * 8 + (threadIdx.x >> 5);
    if (node >= NN) return;
    int lane = threadIdx.x & 31;
    float e1 = 1.0f + eps[l];
    float4 h = ((const float4*)(hin + (long)node * HIDD))[lane];
    float4 acc;
    acc.x = e1 * h.x; acc.y = e1 * h.y; acc.z = e1 * h.z; acc.w = e1 * h.w;
    int jb = rowptr[node], je = rowptr[node + 1];
    for (int j = jb; j < je; j++) {
        int s = csr[j];
        float4 v = ((const float4*)(hin + (long)s * HIDD))[lane];
        acc.x += v.x; acc.y += v.y; acc.z += v.z; acc.w += v.w;
    }
    ((float4*)(A + (long)node * HIDD))[lane] = acc;
}

// ---- fused 2-layer MLP: Y = relu(X@W1+B1)@W2+B2, 32-node tile per block
__global__ __launch_bounds__(256) void k_mlp2(const float* __restrict__ X,
                                              const float* __restrict__ W1, const float* __restrict__ B1,
                                              const float* __restrict__ W2, const float* __restrict__ B2,
                                              float* __restrict__ Y) {
    __shared__ float sX[32 * HIDD];
    __shared__ float sT[32 * HIDD];
    int tid = threadIdx.x;
    long base = (long)blockIdx.x * 32;
    const float4* Xv = (const float4*)(X + base * HIDD);
    float4* sXv = (float4*)sX;
#pragma unroll
    for (int i = 0; i < 4; i++) sXv[tid + 256 * i] = Xv[tid + 256 * i];
    __syncthreads();
    const int fb = (tid & 31) * 4;
    const int nb = (tid >> 5) * 4;
    float acc[4][4];
#pragma unroll
    for (int j = 0; j < 4; j++) { float b = B1[fb + j]; acc[0][j] = b; acc[1][j] = b; acc[2][j] = b; acc[3][j] = b; }
#pragma unroll 4
    for (int k = 0; k < HIDD; k++) {
        float4 w = *(const float4*)(W1 + k * HIDD + fb);
        float a0 = sX[(nb + 0) * HIDD + k], a1 = sX[(nb + 1) * HIDD + k];
        float a2 = sX[(nb + 2) * HIDD + k], a3 = sX[(nb + 3) * HIDD + k];
        acc[0][0] += a0 * w.x; acc[0][1] += a0 * w.y; acc[0][2] += a0 * w.z; acc[0][3] += a0 * w.w;
        acc[1][0] += a1 * w.x; acc[1][1] += a1 * w.y; acc[1][2] += a1 * w.z; acc[1][3] += a1 * w.w;
        acc[2][0] += a2 * w.x; acc[2][1] += a2 * w.y; acc[2][2] += a2 * w.z; acc[2][3] += a2 * w.w;
        acc[3][0] += a3 * w.x; acc[3][1] += a3 * w.y; acc[3][2] += a3 * w.z; acc[3][3] += a3 * w.w;
    }
#pragma unroll
    for (int i = 0; i < 4; i++) {
        float4 v;
        v.x = fmaxf(acc[i][0], 0.f); v.y = fmaxf(acc[i][1], 0.f);
        v.z = fmaxf(acc[i][2], 0.f); v.w = fmaxf(acc[i][3], 0.f);
        *(float4*)(sT + (nb + i) * HIDD + fb) = v;
    }
    __syncthreads();
#pragma unroll
    for (int j = 0; j < 4; j++) { float b = B2[fb + j]; acc[0][j] = b; acc[1][j] = b; acc[2][j] = b; acc[3][j] = b; }
#pragma unroll 4
    for (int k = 0; k < HIDD; k++) {
        float4 w = *(const float4*)(W2 + k * HIDD + fb);
        float a0 = sT[(nb + 0) * HIDD + k], a1 = sT[(nb + 1) * HIDD + k];
        float a2 = sT[(nb + 2) * HIDD + k], a3 = sT[(nb + 3) * HIDD + k];
        acc[0][0] += a0 * w.x; acc[0][1] += a0 * w.y; acc[0][2] += a0 * w.z; acc[0][3] += a0 * w.w;
        acc[1][0] += a1 * w.x; acc[1][1] += a1 * w.y; acc[1][2] += a1 * w.z; acc[1][3] += a1 * w.w;
        acc[2][0] += a2 * w.x; acc[2][1] += a2 * w.y; acc[2][2] += a2 * w.z; acc[2][3] += a2 * w.w;
        acc[3][0] += a3 * w.x; acc[3][1] += a3 * w.y; acc[3][2] += a3 * w.z; acc[3][3] += a3 * w.w;
    }
#pragma unroll
    for (int i = 0; i < 4; i++) {
        float4 v; v.x = acc[i][0]; v.y = acc[i][1]; v.z = acc[i][2]; v.w = acc[i][3];
        *(float4*)(Y + (base + nb + i) * HIDD + fb) = v;
    }
}

// ---- single GEMM + relu: Y = relu(X@W+B)
__global__ __launch_bounds__(256) void k_gemm_relu(const float* __restrict__ X,
                                                   const float* __restrict__ W, const float* __restrict__ B,
                                                   float* __restrict__ Y) {
    __shared__ float sX[32 * HIDD];
    int tid = threadIdx.x;
    long base = (long)blockIdx.x * 32;
    const float4* Xv = (const float4*)(X + base * HIDD);
    float4* sXv = (float4*)sX;
#pragma unroll
    for (int i = 0; i < 4; i++) sXv[tid + 256 * i] = Xv[tid + 256 * i];
    __syncthreads();
    const int fb = (tid & 31) * 4;
    const int nb = (tid >> 5) * 4;
    float acc[4][4];
#pragma unroll
    for (int j = 0; j < 4; j++) { float b = B[fb + j]; acc[0][j] = b; acc[1][j] = b; acc[2][j] = b; acc[3][j] = b; }
#pragma unroll 4
    for (int k = 0; k < HIDD; k++) {
        float4 w = *(const float4*)(W + k * HIDD + fb);
        float a0 = sX[(nb + 0) * HIDD + k], a1 = sX[(nb + 1) * HIDD + k];
        float a2 = sX[(nb + 2) * HIDD + k], a3 = sX[(nb + 3) * HIDD + k];
        acc[0][0] += a0 * w.x; acc[0][1] += a0 * w.y; acc[0][2] += a0 * w.z; acc[0][3] += a0 * w.w;
        acc[1][0] += a1 * w.x; acc[1][1] += a1 * w.y; acc[1][2] += a1 * w.z; acc[1][3] += a1 * w.w;
        acc[2][0] += a2 * w.x; acc[2][1] += a2 * w.y; acc[2][2] += a2 * w.z; acc[2][3] += a2 * w.w;
        acc[3][0] += a3 * w.x; acc[3][1] += a3 * w.y; acc[3][2] += a3 * w.z; acc[3][3] += a3 * w.w;
    }
#pragma unroll
    for (int i = 0; i < 4; i++) {
        float4 v;
        v.x = fmaxf(acc[i][0], 0.f); v.y = fmaxf(acc[i][1], 0.f);
        v.z = fmaxf(acc[i][2], 0.f); v.w = fmaxf(acc[i][3], 0.f);
        *(float4*)(Y + (base + nb + i) * HIDD + fb) = v;
    }
}

// ---- GraphNorm + relu, in-place; one block (512 thr = 4 node-lanes x 128 feats) per graph
__global__ __launch_bounds__(512) void k_gnorm(float* __restrict__ H, const int* __restrict__ goff,
                                               const float* __restrict__ scale,
                                               const float* __restrict__ weight,
                                               const float* __restrict__ bias) {
    int g = blockIdx.x;
    int s = goff[g], e = goff[g + 1];
    float cnt = (float)max(e - s, 1);
    int f = threadIdx.x & 127;
    int r = threadIdx.x >> 7;
    float sum = 0.f, sumsq = 0.f;
    for (int i = s + r; i < e; i += 4) {
        float v = H[(long)i * HIDD + f];
        sum += v; sumsq += v * v;
    }
    __shared__ float red[2][4][128];
    red[0][r][f] = sum; red[1][r][f] = sumsq;
    __syncthreads();
    if (r == 0) {
        sum = red[0][0][f] + red[0][1][f] + red[0][2][f] + red[0][3][f];
        sumsq = red[1][0][f] + red[1][1][f] + red[1][2][f] + red[1][3][f];
        float mean = sum / cnt;
        float ms = mean * scale[f];
        float var = sumsq / cnt - 2.f * ms * mean + ms * ms;
        float inv = weight[f] / sqrtf(var + 1e-8f);
        red[0][0][f] = ms; red[1][0][f] = inv;
    }
    __syncthreads();
    float ms = red[0][0][f], inv = red[1][0][f];
    float b = bias[f];
    for (int i = s + r; i < e; i += 4) {
        long idx = (long)i * HIDD + f;
        float v = (H[idx] - ms) * inv + b;
        H[idx] = v > 0.f ? v : 0.f;
    }
}

// ---- per-graph pooling of z1 [N,128] -> pooled [G,128]
__global__ __launch_bounds__(512) void k_pool(const float* __restrict__ Z, const int* __restrict__ goff,
                                              float* __restrict__ pooled) {
    int g = blockIdx.x;
    int s = goff[g], e = goff[g + 1];
    int f = threadIdx.x & 127;
    int r = threadIdx.x >> 7;
    float sum = 0.f;
    for (int i = s + r; i < e; i += 4) sum += Z[(long)i * HIDD + f];
    __shared__ float red[4][128];
    red[r][f] = sum;
    __syncthreads();
    if (r == 0) pooled[g * HIDD + f] = red[0][f] + red[1][f] + red[2][f] + red[3][f];
}

// ---- out[g, l*64+t] = pooled[g] @ pw2 + count*pb2
__global__ __launch_bounds__(64) void k_out(const float* __restrict__ pooled, const int* __restrict__ goff,
                                            const float* __restrict__ W, const float* __restrict__ B,
                                            float* __restrict__ out, int l) {
    int g = blockIdx.x;
    int t = threadIdx.x;
    __shared__ float p[128];
    p[t] = pooled[g * HIDD + t];
    p[t + 64] = pooled[g * HIDD + 64 + t];
    __syncthreads();
    float cnt = (float)(goff[g + 1] - goff[g]);
    float acc = cnt * B[t];
    for (int k = 0; k < HIDD; k++) acc += p[k] * W[k * TGTT + t];
    out[(long)g * (3 * TGTT) + l * TGTT + t] = acc;
}

extern "C" void kernel_launch(void* const* d_in, const int* in_sizes, int n_in,
                              void* d_out, int out_size, void* d_ws, size_t ws_size,
                              hipStream_t stream) {
    const float* x    = (const float*)d_in[0];
    const int*   ei   = (const int*)d_in[1];
    const int*   batch= (const int*)d_in[2];
    const float* cw1  = (const float*)d_in[3];
    const float* cb1  = (const float*)d_in[4];
    const float* cw2  = (const float*)d_in[5];
    const float* cb2  = (const float*)d_in[6];
    const float* eps  = (const float*)d_in[7];
    const float* gsc  = (const float*)d_in[8];
    const float* gw   = (const float*)d_in[9];
    const float* gb   = (const float*)d_in[10];
    const float* pw1  = (const float*)d_in[11];
    const float* pb1  = (const float*)d_in[12];
    const float* pw2  = (const float*)d_in[13];
    const float* pb2  = (const float*)d_in[14];
    float* out = (float*)d_out;

    float* H      = (float*)d_ws;                        // N*128 f32
    float* A      = H + (size_t)NN * HIDD;               // N*128 f32
    float* pooled = A + (size_t)NN * HIDD;               // G*128 f32
    int*   goff   = (int*)(pooled + (size_t)GGG * HIDD); // G+1
    int*   rowptr = goff + (GGG + 1);                    // N+1
    int*   deg    = rowptr + (NN + 1);                   // N
    int*   cursor = deg + NN;                            // N
    int*   bsum   = cursor + NN;                         // NSB
    int*   csr    = bsum + NSB;                          // E

    k_goff<<<3, 256, 0, stream>>>(batch, goff);

    // ---- CSR build (deg and cursor must start at zero every call)
    hipMemsetAsync(deg, 0, (size_t)(2 * NN) * sizeof(int), stream);  // deg + cursor contiguous
    k_count<<<(EE + 255) / 256, 256, 0, stream>>>(ei, deg);
    k_bsum<<<NSB, SCANB, 0, stream>>>(deg, bsum);
    k_bscan<<<1, 64, 0, stream>>>(bsum, rowptr);
    k_scan<<<NSB, SCANB, 0, stream>>>(deg, bsum, rowptr);
    k_fill<<<(EE + 255) / 256, 256, 0, stream>>>(ei, rowptr, cursor, csr);

    for (int l = 0; l < 3; l++) {
        const float* hin = (l == 0) ? x : H;
        k_gather<<<(NN + 7) / 8, 256, 0, stream>>>(hin, rowptr, csr, eps, l, A);
        k_mlp2<<<NN / 32, 256, 0, stream>>>(A, cw1 + (size_t)l * HIDD * HIDD, cb1 + l * HIDD,
                                            cw2 + (size_t)l * HIDD * HIDD, cb2 + l * HIDD, H);
        k_gnorm<<<GGG, 512, 0, stream>>>(H, goff, gsc + l * HIDD, gw + l * HIDD, gb + l * HIDD);
        k_gemm_relu<<<NN / 32, 256, 0, stream>>>(H, pw1 + (size_t)l * HIDD * HIDD, pb1 + l * HIDD, A);
        k_pool<<<GGG, 512, 0, stream>>>(A, goff, pooled);
        k_out<<<GGG, 64, 0, stream>>>(pooled, goff, pw2 + (size_t)l * HIDD * TGTT, pb2 + l * TGTT, out, l);
    }
}

// Round 3
// 1024.187 us; speedup vs baseline: 4.7166x; 1.3411x over previous
//
#include <hip/hip_runtime.h>

#define NN 100000
#define EE 1600000
#define HIDD 128
#define TGTT 64
#define GGG 512
#define SCANB 1024
#define NSB ((NN + SCANB - 1) / SCANB)

typedef unsigned short ushort_t;
typedef __attribute__((ext_vector_type(8))) short short8;
typedef __attribute__((ext_vector_type(4))) float f32x4;
typedef __attribute__((ext_vector_type(4))) unsigned short us4;

__device__ __forceinline__ float b2f(ushort_t u) {
    union { unsigned int i; float f; } v; v.i = ((unsigned int)u) << 16; return v.f;
}
__device__ __forceinline__ ushort_t f2b(float f) {
    union { float f; unsigned int i; } v; v.f = f;
    unsigned int r = (v.i + 0x7fffu + ((v.i >> 16) & 1u)) >> 16;
    return (ushort_t)r;
}

// ---- per-graph offsets (batch sorted)
__global__ void k_goff(const int* __restrict__ batch, int* __restrict__ goff) {
    int t = blockIdx.x * blockDim.x + threadIdx.x;
    if (t > GGG) return;
    int lo = 0, hi = NN;
    while (lo < hi) { int mid = (lo + hi) >> 1; if (batch[mid] < t) lo = mid + 1; else hi = mid; }
    goff[t] = lo;
}

// ---- x fp32 -> bf16
__global__ __launch_bounds__(256) void k_cvt(const float* __restrict__ x, ushort_t* __restrict__ Xb) {
    long i = (long)blockIdx.x * 256 + threadIdx.x;
    if (i >= (long)NN * 32) return;
    float4 v = ((const float4*)x)[i];
    us4 o; o.x = f2b(v.x); o.y = f2b(v.y); o.z = f2b(v.z); o.w = f2b(v.w);
    ((us4*)Xb)[i] = o;
}

// ---- weight prep: Wt[mat][n][k] = bf16(W[mat][k][n]), 9 mats of 128x128
__global__ __launch_bounds__(256) void k_prep(const float* __restrict__ cw1, const float* __restrict__ cw2,
                                              const float* __restrict__ pw1, ushort_t* __restrict__ Wt) {
    __shared__ ushort_t sW[128 * 129];
    int mat = blockIdx.x;
    int l = mat / 3, j = mat % 3;
    const float* src = (j == 0 ? cw1 : j == 1 ? cw2 : pw1) + (size_t)l * HIDD * HIDD;
    ushort_t* dst = Wt + (size_t)mat * HIDD * HIDD;
    for (int i = threadIdx.x; i < HIDD * HIDD; i += 256) {
        int k = i >> 7, n = i & 127;
        sW[n * 129 + k] = f2b(src[i]);            // coalesced read, banked LDS write
    }
    __syncthreads();
    for (int i = threadIdx.x; i < HIDD * HIDD; i += 256) {
        dst[i] = sW[(i >> 7) * 129 + (i & 127)];  // coalesced write
    }
}

// ======================= CSR build =======================
__global__ __launch_bounds__(256) void k_count(const int* __restrict__ ei, int* __restrict__ deg) {
    int e = blockIdx.x * 256 + threadIdx.x;
    if (e >= EE) return;
    atomicAdd(&deg[ei[EE + e]], 1);
}

__global__ __launch_bounds__(SCANB) void k_bsum(const int* __restrict__ deg, int* __restrict__ bsum) {
    __shared__ int sd[SCANB];
    int i = blockIdx.x * SCANB + threadIdx.x;
    sd[threadIdx.x] = (i < NN) ? deg[i] : 0;
    __syncthreads();
    for (int off = SCANB / 2; off > 0; off >>= 1) {
        if (threadIdx.x < off) sd[threadIdx.x] += sd[threadIdx.x + off];
        __syncthreads();
    }
    if (threadIdx.x == 0) bsum[blockIdx.x] = sd[0];
}

__global__ void k_bscan(int* __restrict__ bsum, int* __restrict__ rowptr) {
    if (threadIdx.x == 0) {
        int acc = 0;
        for (int b = 0; b < NSB; b++) { int v = bsum[b]; bsum[b] = acc; acc += v; }
        rowptr[NN] = acc;
    }
}

__global__ __launch_bounds__(SCANB) void k_scan(const int* __restrict__ deg, const int* __restrict__ bsum,
                                                int* __restrict__ rowptr) {
    __shared__ int sd[SCANB];
    int i = blockIdx.x * SCANB + threadIdx.x;
    int v = (i < NN) ? deg[i] : 0;
    sd[threadIdx.x] = v;
    __syncthreads();
    for (int off = 1; off < SCANB; off <<= 1) {
        int t = (threadIdx.x >= off) ? sd[threadIdx.x - off] : 0;
        __syncthreads();
        sd[threadIdx.x] += t;
        __syncthreads();
    }
    if (i < NN) rowptr[i] = bsum[blockIdx.x] + sd[threadIdx.x] - v;
}

__global__ __launch_bounds__(256) void k_fill(const int* __restrict__ ei, const int* __restrict__ rowptr,
                                              int* __restrict__ cursor, int* __restrict__ csr) {
    int e = blockIdx.x * 256 + threadIdx.x;
    if (e >= EE) return;
    int s = ei[e], d = ei[EE + e];
    int pos = rowptr[d] + atomicAdd(&cursor[d], 1);
    csr[pos] = s;
}

// ======================= gather (bf16): A[i] = (1+eps)*h[i] + sum_j h[csr[j]] ===================
__global__ __launch_bounds__(256) void k_gather(const ushort_t* __restrict__ hin,
                                                const int* __restrict__ rowptr,
                                                const int* __restrict__ csr,
                                                const float* __restrict__ eps, int l,
                                                ushort_t* __restrict__ A) {
    int node = blockIdx.x * 8 + (threadIdx.x >> 5);
    if (node >= NN) return;
    int lane = threadIdx.x & 31;
    float e1 = 1.0f + eps[l];
    us4 h = ((const us4*)(hin + (long)node * HIDD))[lane];
    float ax = e1 * b2f(h.x), ay = e1 * b2f(h.y), az = e1 * b2f(h.z), aw = e1 * b2f(h.w);
    int jb = rowptr[node], je = rowptr[node + 1];
    for (int j = jb; j < je; j++) {
        int s = csr[j];
        us4 v = ((const us4*)(hin + (long)s * HIDD))[lane];
        ax += b2f(v.x); ay += b2f(v.y); az += b2f(v.z); aw += b2f(v.w);
    }
    us4 o; o.x = f2b(ax); o.y = f2b(ay); o.z = f2b(az); o.w = f2b(aw);
    ((us4*)(A + (long)node * HIDD))[lane] = o;
}

// ======================= MFMA fused 2-layer MLP: Y = relu(X@W1+B1)@W2+B2 ======================
// X, Y bf16 [N,128]; Wt1, Wt2 bf16 transposed [n][k]; 64 nodes/block, 4 waves.
#define LSTR 136
__global__ __launch_bounds__(256) void k_mlp2(const ushort_t* __restrict__ X,
                                              const ushort_t* __restrict__ Wt1, const float* __restrict__ B1,
                                              const ushort_t* __restrict__ Wt2, const float* __restrict__ B2,
                                              ushort_t* __restrict__ Y) {
    __shared__ ushort_t sX[64 * LSTR];
    __shared__ ushort_t sT[64 * LSTR];
    int tid = threadIdx.x;
    long base = (long)blockIdx.x * 64;
#pragma unroll
    for (int c = 0; c < 4; c++) {
        int idx = c * 256 + tid;
        int row = idx >> 4, cw = idx & 15;
        long grow = base + row;
        short8 v = (short8)0;
        if (grow < NN) v = *(const short8*)(X + (grow << 7) + (cw << 3));
        *(short8*)(sX + row * LSTR + (cw << 3)) = v;
    }
    __syncthreads();

    int w = tid >> 6, lane = tid & 63, q = lane >> 4, l16 = lane & 15;

    // ---- GEMM1: sX @ Wt1 -> relu -> sT
    {
        const ushort_t* aB = sX + (w * 16 + l16) * LSTR + q * 8;
        short8 a0 = *(const short8*)(aB);
        short8 a1 = *(const short8*)(aB + 32);
        short8 a2 = *(const short8*)(aB + 64);
        short8 a3 = *(const short8*)(aB + 96);
#pragma unroll
        for (int nt = 0; nt < 8; nt++) {
            int col = nt * 16 + l16;
            float bias = B1[col];
            f32x4 acc = {bias, bias, bias, bias};
            const ushort_t* bB = Wt1 + col * HIDD + q * 8;
            short8 b0 = *(const short8*)(bB);
            short8 b1 = *(const short8*)(bB + 32);
            short8 b2 = *(const short8*)(bB + 64);
            short8 b3 = *(const short8*)(bB + 96);
            acc = __builtin_amdgcn_mfma_f32_16x16x32_bf16(a0, b0, acc, 0, 0, 0);
            acc = __builtin_amdgcn_mfma_f32_16x16x32_bf16(a1, b1, acc, 0, 0, 0);
            acc = __builtin_amdgcn_mfma_f32_16x16x32_bf16(a2, b2, acc, 0, 0, 0);
            acc = __builtin_amdgcn_mfma_f32_16x16x32_bf16(a3, b3, acc, 0, 0, 0);
#pragma unroll
            for (int r = 0; r < 4; r++) {
                float v = fmaxf(acc[r], 0.f);
                sT[(w * 16 + q * 4 + r) * LSTR + col] = f2b(v);
            }
        }
    }
    __syncthreads();

    // ---- GEMM2: sT @ Wt2 + B2 -> Y (bf16)
    {
        const ushort_t* aB = sT + (w * 16 + l16) * LSTR + q * 8;
        short8 a0 = *(const short8*)(aB);
        short8 a1 = *(const short8*)(aB + 32);
        short8 a2 = *(const short8*)(aB + 64);
        short8 a3 = *(const short8*)(aB + 96);
#pragma unroll
        for (int nt = 0; nt < 8; nt++) {
            int col = nt * 16 + l16;
            float bias = B2[col];
            f32x4 acc = {bias, bias, bias, bias};
            const ushort_t* bB = Wt2 + col * HIDD + q * 8;
            short8 b0 = *(const short8*)(bB);
            short8 b1 = *(const short8*)(bB + 32);
            short8 b2 = *(const short8*)(bB + 64);
            short8 b3 = *(const short8*)(bB + 96);
            acc = __builtin_amdgcn_mfma_f32_16x16x32_bf16(a0, b0, acc, 0, 0, 0);
            acc = __builtin_amdgcn_mfma_f32_16x16x32_bf16(a1, b1, acc, 0, 0, 0);
            acc = __builtin_amdgcn_mfma_f32_16x16x32_bf16(a2, b2, acc, 0, 0, 0);
            acc = __builtin_amdgcn_mfma_f32_16x16x32_bf16(a3, b3, acc, 0, 0, 0);
#pragma unroll
            for (int r = 0; r < 4; r++) {
                long row = base + w * 16 + q * 4 + r;
                if (row < NN) Y[(row << 7) + col] = f2b(acc[r]);
            }
        }
    }
}

// ======================= MFMA single GEMM + relu: Z = relu(X@W+B), bf16 out ==================
__global__ __launch_bounds__(256) void k_gemm_relu(const ushort_t* __restrict__ X,
                                                   const ushort_t* __restrict__ Wt, const float* __restrict__ B,
                                                   ushort_t* __restrict__ Z) {
    __shared__ ushort_t sX[64 * LSTR];
    int tid = threadIdx.x;
    long base = (long)blockIdx.x * 64;
#pragma unroll
    for (int c = 0; c < 4; c++) {
        int idx = c * 256 + tid;
        int row = idx >> 4, cw = idx & 15;
        long grow = base + row;
        short8 v = (short8)0;
        if (grow < NN) v = *(const short8*)(X + (grow << 7) + (cw << 3));
        *(short8*)(sX + row * LSTR + (cw << 3)) = v;
    }
    __syncthreads();

    int w = tid >> 6, lane = tid & 63, q = lane >> 4, l16 = lane & 15;
    const ushort_t* aB = sX + (w * 16 + l16) * LSTR + q * 8;
    short8 a0 = *(const short8*)(aB);
    short8 a1 = *(const short8*)(aB + 32);
    short8 a2 = *(const short8*)(aB + 64);
    short8 a3 = *(const short8*)(aB + 96);
#pragma unroll
    for (int nt = 0; nt < 8; nt++) {
        int col = nt * 16 + l16;
        float bias = B[col];
        f32x4 acc = {bias, bias, bias, bias};
        const ushort_t* bB = Wt + col * HIDD + q * 8;
        short8 b0 = *(const short8*)(bB);
        short8 b1 = *(const short8*)(bB + 32);
        short8 b2 = *(const short8*)(bB + 64);
        short8 b3 = *(const short8*)(bB + 96);
        acc = __builtin_amdgcn_mfma_f32_16x16x32_bf16(a0, b0, acc, 0, 0, 0);
        acc = __builtin_amdgcn_mfma_f32_16x16x32_bf16(a1, b1, acc, 0, 0, 0);
        acc = __builtin_amdgcn_mfma_f32_16x16x32_bf16(a2, b2, acc, 0, 0, 0);
        acc = __builtin_amdgcn_mfma_f32_16x16x32_bf16(a3, b3, acc, 0, 0, 0);
#pragma unroll
        for (int r = 0; r < 4; r++) {
            long row = base + w * 16 + q * 4 + r;
            if (row < NN) Z[(row << 7) + col] = f2b(fmaxf(acc[r], 0.f));
        }
    }
}

// ---- GraphNorm + relu (bf16 in-place)
__global__ __launch_bounds__(512) void k_gnorm(ushort_t* __restrict__ H, const int* __restrict__ goff,
                                               const float* __restrict__ scale,
                                               const float* __restrict__ weight,
                                               const float* __restrict__ bias) {
    int g = blockIdx.x;
    int s = goff[g], e = goff[g + 1];
    float cnt = (float)max(e - s, 1);
    int f = threadIdx.x & 127;
    int r = threadIdx.x >> 7;
    float sum = 0.f, sumsq = 0.f;
    for (int i = s + r; i < e; i += 4) {
        float v = b2f(H[(long)i * HIDD + f]);
        sum += v; sumsq += v * v;
    }
    __shared__ float red[2][4][128];
    red[0][r][f] = sum; red[1][r][f] = sumsq;
    __syncthreads();
    if (r == 0) {
        sum = red[0][0][f] + red[0][1][f] + red[0][2][f] + red[0][3][f];
        sumsq = red[1][0][f] + red[1][1][f] + red[1][2][f] + red[1][3][f];
        float mean = sum / cnt;
        float ms = mean * scale[f];
        float var = sumsq / cnt - 2.f * ms * mean + ms * ms;
        float inv = weight[f] / sqrtf(var + 1e-8f);
        red[0][0][f] = ms; red[1][0][f] = inv;
    }
    __syncthreads();
    float ms = red[0][0][f], inv = red[1][0][f];
    float b = bias[f];
    for (int i = s + r; i < e; i += 4) {
        long idx = (long)i * HIDD + f;
        float v = (b2f(H[idx]) - ms) * inv + b;
        H[idx] = f2b(v > 0.f ? v : 0.f);
    }
}

// ---- per-graph pooling of bf16 Z -> pooled fp32 [G,128]
__global__ __launch_bounds__(512) void k_pool(const ushort_t* __restrict__ Z, const int* __restrict__ goff,
                                              float* __restrict__ pooled) {
    int g = blockIdx.x;
    int s = goff[g], e = goff[g + 1];
    int f = threadIdx.x & 127;
    int r = threadIdx.x >> 7;
    float sum = 0.f;
    for (int i = s + r; i < e; i += 4) sum += b2f(Z[(long)i * HIDD + f]);
    __shared__ float red[4][128];
    red[r][f] = sum;
    __syncthreads();
    if (r == 0) pooled[g * HIDD + f] = red[0][f] + red[1][f] + red[2][f] + red[3][f];
}

// ---- out[g, l*64+t] = pooled[g] @ pw2 + count*pb2  (fp32)
__global__ __launch_bounds__(64) void k_out(const float* __restrict__ pooled, const int* __restrict__ goff,
                                            const float* __restrict__ W, const float* __restrict__ B,
                                            float* __restrict__ out, int l) {
    int g = blockIdx.x;
    int t = threadIdx.x;
    __shared__ float p[128];
    p[t] = pooled[g * HIDD + t];
    p[t + 64] = pooled[g * HIDD + 64 + t];
    __syncthreads();
    float cnt = (float)(goff[g + 1] - goff[g]);
    float acc = cnt * B[t];
    for (int k = 0; k < HIDD; k++) acc += p[k] * W[k * TGTT + t];
    out[(long)g * (3 * TGTT) + l * TGTT + t] = acc;
}

extern "C" void kernel_launch(void* const* d_in, const int* in_sizes, int n_in,
                              void* d_out, int out_size, void* d_ws, size_t ws_size,
                              hipStream_t stream) {
    const float* x    = (const float*)d_in[0];
    const int*   ei   = (const int*)d_in[1];
    const int*   batch= (const int*)d_in[2];
    const float* cw1  = (const float*)d_in[3];
    const float* cb1  = (const float*)d_in[4];
    const float* cw2  = (const float*)d_in[5];
    const float* cb2  = (const float*)d_in[6];
    const float* eps  = (const float*)d_in[7];
    const float* gsc  = (const float*)d_in[8];
    const float* gw   = (const float*)d_in[9];
    const float* gb   = (const float*)d_in[10];
    const float* pw1  = (const float*)d_in[11];
    const float* pb1  = (const float*)d_in[12];
    const float* pw2  = (const float*)d_in[13];
    const float* pb2  = (const float*)d_in[14];
    float* out = (float*)d_out;

    ushort_t* Xb = (ushort_t*)d_ws;                       // N*128 bf16
    ushort_t* A  = Xb + (size_t)NN * HIDD;                // N*128 bf16 (also Z)
    ushort_t* H  = A + (size_t)NN * HIDD;                 // N*128 bf16
    ushort_t* Wt = H + (size_t)NN * HIDD;                 // 9*128*128 bf16
    float* pooled = (float*)(Wt + (size_t)9 * HIDD * HIDD); // G*128 f32
    int* goff   = (int*)(pooled + (size_t)GGG * HIDD);    // G+1
    int* rowptr = goff + (GGG + 1);                       // N+1
    int* deg    = rowptr + (NN + 1);                      // N
    int* cursor = deg + NN;                               // N
    int* bsum   = cursor + NN;                            // NSB
    int* csr    = bsum + NSB;                             // E

    k_goff<<<3, 256, 0, stream>>>(batch, goff);
    k_cvt<<<(int)(((long)NN * 32 + 255) / 256), 256, 0, stream>>>(x, Xb);
    k_prep<<<9, 256, 0, stream>>>(cw1, cw2, pw1, Wt);

    hipMemsetAsync(deg, 0, (size_t)(2 * NN) * sizeof(int), stream);
    k_count<<<(EE + 255) / 256, 256, 0, stream>>>(ei, deg);
    k_bsum<<<NSB, SCANB, 0, stream>>>(deg, bsum);
    k_bscan<<<1, 64, 0, stream>>>(bsum, rowptr);
    k_scan<<<NSB, SCANB, 0, stream>>>(deg, bsum, rowptr);
    k_fill<<<(EE + 255) / 256, 256, 0, stream>>>(ei, rowptr, cursor, csr);

    for (int l = 0; l < 3; l++) {
        const ushort_t* hin = (l == 0) ? Xb : H;
        ushort_t* Wt1 = Wt + (size_t)(l * 3 + 0) * HIDD * HIDD;
        ushort_t* Wt2 = Wt + (size_t)(l * 3 + 1) * HIDD * HIDD;
        ushort_t* Wtp = Wt + (size_t)(l * 3 + 2) * HIDD * HIDD;
        k_gather<<<(NN + 7) / 8, 256, 0, stream>>>(hin, rowptr, csr, eps, l, A);
        k_mlp2<<<(NN + 63) / 64, 256, 0, stream>>>(A, Wt1, cb1 + l * HIDD, Wt2, cb2 + l * HIDD, H);
        k_gnorm<<<GGG, 512, 0, stream>>>(H, goff, gsc + l * HIDD, gw + l * HIDD, gb + l * HIDD);
        k_gemm_relu<<<(NN + 63) / 64, 256, 0, stream>>>(H, Wtp, pb1 + l * HIDD, A);
        k_pool<<<GGG, 512, 0, stream>>>(A, goff, pooled);
        k_out<<<GGG, 64, 0, stream>>>(pooled, goff, pw2 + (size_t)l * HIDD * TGTT, pb2 + l * TGTT, out, l);
    }
}

// Round 4
// 912.481 us; speedup vs baseline: 5.2941x; 1.1224x over previous
//
#include <hip/hip_runtime.h>

#define NN 100000
#define EE 1600000
#define HIDD 128
#define TGTT 64
#define GGG 512
#define SCANB 1024
#define NSB ((NN + SCANB - 1) / SCANB)

typedef unsigned short ushort_t;
typedef __attribute__((ext_vector_type(8))) short short8;
typedef __attribute__((ext_vector_type(4))) float f32x4;
typedef __attribute__((ext_vector_type(4))) unsigned short us4;

__device__ __forceinline__ float b2f(ushort_t u) {
    union { unsigned int i; float f; } v; v.i = ((unsigned int)u) << 16; return v.f;
}
__device__ __forceinline__ ushort_t f2b(float f) {
    union { float f; unsigned int i; } v; v.f = f;
    unsigned int r = (v.i + 0x7fffu + ((v.i >> 16) & 1u)) >> 16;
    return (ushort_t)r;
}

// ---- per-graph offsets (batch sorted)
__global__ void k_goff(const int* __restrict__ batch, int* __restrict__ goff) {
    int t = blockIdx.x * blockDim.x + threadIdx.x;
    if (t > GGG) return;
    int lo = 0, hi = NN;
    while (lo < hi) { int mid = (lo + hi) >> 1; if (batch[mid] < t) lo = mid + 1; else hi = mid; }
    goff[t] = lo;
}

// ---- x fp32 -> bf16
__global__ __launch_bounds__(256) void k_cvt(const float* __restrict__ x, ushort_t* __restrict__ Xb) {
    long i = (long)blockIdx.x * 256 + threadIdx.x;
    if (i >= (long)NN * 32) return;
    float4 v = ((const float4*)x)[i];
    us4 o; o.x = f2b(v.x); o.y = f2b(v.y); o.z = f2b(v.z); o.w = f2b(v.w);
    ((us4*)Xb)[i] = o;
}

// ---- weight prep: Wt[mat][n][k] = bf16(W[mat][k][n]), 9 mats of 128x128
__global__ __launch_bounds__(256) void k_prep(const float* __restrict__ cw1, const float* __restrict__ cw2,
                                              const float* __restrict__ pw1, ushort_t* __restrict__ Wt) {
    __shared__ ushort_t sW[128 * 129];
    int mat = blockIdx.x;
    int l = mat / 3, j = mat % 3;
    const float* src = (j == 0 ? cw1 : j == 1 ? cw2 : pw1) + (size_t)l * HIDD * HIDD;
    ushort_t* dst = Wt + (size_t)mat * HIDD * HIDD;
    for (int i = threadIdx.x; i < HIDD * HIDD; i += 256) {
        int k = i >> 7, n = i & 127;
        sW[n * 129 + k] = f2b(src[i]);
    }
    __syncthreads();
    for (int i = threadIdx.x; i < HIDD * HIDD; i += 256) {
        dst[i] = sW[(i >> 7) * 129 + (i & 127)];
    }
}

// ======================= CSR build =======================
__global__ __launch_bounds__(256) void k_count(const int* __restrict__ ei, int* __restrict__ deg) {
    int e = blockIdx.x * 256 + threadIdx.x;
    if (e >= EE) return;
    atomicAdd(&deg[ei[EE + e]], 1);
}

__global__ __launch_bounds__(SCANB) void k_bsum(const int* __restrict__ deg, int* __restrict__ bsum) {
    __shared__ int sd[SCANB];
    int i = blockIdx.x * SCANB + threadIdx.x;
    sd[threadIdx.x] = (i < NN) ? deg[i] : 0;
    __syncthreads();
    for (int off = SCANB / 2; off > 0; off >>= 1) {
        if (threadIdx.x < off) sd[threadIdx.x] += sd[threadIdx.x + off];
        __syncthreads();
    }
    if (threadIdx.x == 0) bsum[blockIdx.x] = sd[0];
}

__global__ void k_bscan(int* __restrict__ bsum, int* __restrict__ rowptr) {
    if (threadIdx.x == 0) {
        int acc = 0;
        for (int b = 0; b < NSB; b++) { int v = bsum[b]; bsum[b] = acc; acc += v; }
        rowptr[NN] = acc;
    }
}

__global__ __launch_bounds__(SCANB) void k_scan(const int* __restrict__ deg, const int* __restrict__ bsum,
                                                int* __restrict__ rowptr) {
    __shared__ int sd[SCANB];
    int i = blockIdx.x * SCANB + threadIdx.x;
    int v = (i < NN) ? deg[i] : 0;
    sd[threadIdx.x] = v;
    __syncthreads();
    for (int off = 1; off < SCANB; off <<= 1) {
        int t = (threadIdx.x >= off) ? sd[threadIdx.x - off] : 0;
        __syncthreads();
        sd[threadIdx.x] += t;
        __syncthreads();
    }
    if (i < NN) rowptr[i] = bsum[blockIdx.x] + sd[threadIdx.x] - v;
}

__global__ __launch_bounds__(256) void k_fill(const int* __restrict__ ei, const int* __restrict__ rowptr,
                                              int* __restrict__ cursor, int* __restrict__ csr) {
    int e = blockIdx.x * 256 + threadIdx.x;
    if (e >= EE) return;
    int s = ei[e], d = ei[EE + e];
    int pos = rowptr[d] + atomicAdd(&cursor[d], 1);
    csr[pos] = s;
}

// ======================= gather (bf16): A[i] = (1+eps)*h[i] + sum_j h[csr[j]] ===================
// 16 lanes/node (16 B each), 16 nodes per 256-thread block (4 independent chains per wave),
// 4-deep unrolled loads for memory-level parallelism.
__global__ __launch_bounds__(256) void k_gather(const ushort_t* __restrict__ hin,
                                                const int* __restrict__ rowptr,
                                                const int* __restrict__ csr,
                                                const float* __restrict__ eps, int l,
                                                ushort_t* __restrict__ A) {
    int node = blockIdx.x * 16 + (threadIdx.x >> 4);
    if (node >= NN) return;
    int lane = threadIdx.x & 15;
    int off = lane << 3;
    float e1 = 1.0f + eps[l];
    short8 h = *(const short8*)(hin + ((long)node << 7) + off);
    float acc[8];
#pragma unroll
    for (int t = 0; t < 8; t++) acc[t] = e1 * b2f((ushort_t)h[t]);
    int jb = rowptr[node], je = rowptr[node + 1];
    int j = jb;
    for (; j + 4 <= je; j += 4) {
        int s0 = csr[j], s1 = csr[j + 1], s2 = csr[j + 2], s3 = csr[j + 3];
        short8 v0 = *(const short8*)(hin + ((long)s0 << 7) + off);
        short8 v1 = *(const short8*)(hin + ((long)s1 << 7) + off);
        short8 v2 = *(const short8*)(hin + ((long)s2 << 7) + off);
        short8 v3 = *(const short8*)(hin + ((long)s3 << 7) + off);
#pragma unroll
        for (int t = 0; t < 8; t++)
            acc[t] += (b2f((ushort_t)v0[t]) + b2f((ushort_t)v1[t])) +
                      (b2f((ushort_t)v2[t]) + b2f((ushort_t)v3[t]));
    }
    for (; j < je; j++) {
        int s = csr[j];
        short8 v = *(const short8*)(hin + ((long)s << 7) + off);
#pragma unroll
        for (int t = 0; t < 8; t++) acc[t] += b2f((ushort_t)v[t]);
    }
    short8 o;
#pragma unroll
    for (int t = 0; t < 8; t++) o[t] = (short)f2b(acc[t]);
    *(short8*)(A + ((long)node << 7) + off) = o;
}

// ======================= MFMA fused 2-layer MLP: Y = relu(X@W1+B1)@W2+B2 ======================
#define LSTR 136
__global__ __launch_bounds__(256) void k_mlp2(const ushort_t* __restrict__ X,
                                              const ushort_t* __restrict__ Wt1, const float* __restrict__ B1,
                                              const ushort_t* __restrict__ Wt2, const float* __restrict__ B2,
                                              ushort_t* __restrict__ Y) {
    __shared__ ushort_t sX[64 * LSTR];
    __shared__ ushort_t sT[64 * LSTR];
    int tid = threadIdx.x;
    long base = (long)blockIdx.x * 64;
#pragma unroll
    for (int c = 0; c < 4; c++) {
        int idx = c * 256 + tid;
        int row = idx >> 4, cw = idx & 15;
        long grow = base + row;
        short8 v = (short8)0;
        if (grow < NN) v = *(const short8*)(X + (grow << 7) + (cw << 3));
        *(short8*)(sX + row * LSTR + (cw << 3)) = v;
    }
    __syncthreads();

    int w = tid >> 6, lane = tid & 63, q = lane >> 4, l16 = lane & 15;

    {
        const ushort_t* aB = sX + (w * 16 + l16) * LSTR + q * 8;
        short8 a0 = *(const short8*)(aB);
        short8 a1 = *(const short8*)(aB + 32);
        short8 a2 = *(const short8*)(aB + 64);
        short8 a3 = *(const short8*)(aB + 96);
#pragma unroll
        for (int nt = 0; nt < 8; nt++) {
            int col = nt * 16 + l16;
            float bias = B1[col];
            f32x4 acc = {bias, bias, bias, bias};
            const ushort_t* bB = Wt1 + col * HIDD + q * 8;
            short8 b0 = *(const short8*)(bB);
            short8 b1 = *(const short8*)(bB + 32);
            short8 b2 = *(const short8*)(bB + 64);
            short8 b3 = *(const short8*)(bB + 96);
            acc = __builtin_amdgcn_mfma_f32_16x16x32_bf16(a0, b0, acc, 0, 0, 0);
            acc = __builtin_amdgcn_mfma_f32_16x16x32_bf16(a1, b1, acc, 0, 0, 0);
            acc = __builtin_amdgcn_mfma_f32_16x16x32_bf16(a2, b2, acc, 0, 0, 0);
            acc = __builtin_amdgcn_mfma_f32_16x16x32_bf16(a3, b3, acc, 0, 0, 0);
#pragma unroll
            for (int r = 0; r < 4; r++) {
                float v = fmaxf(acc[r], 0.f);
                sT[(w * 16 + q * 4 + r) * LSTR + col] = f2b(v);
            }
        }
    }
    __syncthreads();

    {
        const ushort_t* aB = sT + (w * 16 + l16) * LSTR + q * 8;
        short8 a0 = *(const short8*)(aB);
        short8 a1 = *(const short8*)(aB + 32);
        short8 a2 = *(const short8*)(aB + 64);
        short8 a3 = *(const short8*)(aB + 96);
#pragma unroll
        for (int nt = 0; nt < 8; nt++) {
            int col = nt * 16 + l16;
            float bias = B2[col];
            f32x4 acc = {bias, bias, bias, bias};
            const ushort_t* bB = Wt2 + col * HIDD + q * 8;
            short8 b0 = *(const short8*)(bB);
            short8 b1 = *(const short8*)(bB + 32);
            short8 b2 = *(const short8*)(bB + 64);
            short8 b3 = *(const short8*)(bB + 96);
            acc = __builtin_amdgcn_mfma_f32_16x16x32_bf16(a0, b0, acc, 0, 0, 0);
            acc = __builtin_amdgcn_mfma_f32_16x16x32_bf16(a1, b1, acc, 0, 0, 0);
            acc = __builtin_amdgcn_mfma_f32_16x16x32_bf16(a2, b2, acc, 0, 0, 0);
            acc = __builtin_amdgcn_mfma_f32_16x16x32_bf16(a3, b3, acc, 0, 0, 0);
#pragma unroll
            for (int r = 0; r < 4; r++) {
                long row = base + w * 16 + q * 4 + r;
                if (row < NN) Y[(row << 7) + col] = f2b(acc[r]);
            }
        }
    }
}

// ======================= MFMA single GEMM + relu ==================
__global__ __launch_bounds__(256) void k_gemm_relu(const ushort_t* __restrict__ X,
                                                   const ushort_t* __restrict__ Wt, const float* __restrict__ B,
                                                   ushort_t* __restrict__ Z) {
    __shared__ ushort_t sX[64 * LSTR];
    int tid = threadIdx.x;
    long base = (long)blockIdx.x * 64;
#pragma unroll
    for (int c = 0; c < 4; c++) {
        int idx = c * 256 + tid;
        int row = idx >> 4, cw = idx & 15;
        long grow = base + row;
        short8 v = (short8)0;
        if (grow < NN) v = *(const short8*)(X + (grow << 7) + (cw << 3));
        *(short8*)(sX + row * LSTR + (cw << 3)) = v;
    }
    __syncthreads();

    int w = tid >> 6, lane = tid & 63, q = lane >> 4, l16 = lane & 15;
    const ushort_t* aB = sX + (w * 16 + l16) * LSTR + q * 8;
    short8 a0 = *(const short8*)(aB);
    short8 a1 = *(const short8*)(aB + 32);
    short8 a2 = *(const short8*)(aB + 64);
    short8 a3 = *(const short8*)(aB + 96);
#pragma unroll
    for (int nt = 0; nt < 8; nt++) {
        int col = nt * 16 + l16;
        float bias = B[col];
        f32x4 acc = {bias, bias, bias, bias};
        const ushort_t* bB = Wt + col * HIDD + q * 8;
        short8 b0 = *(const short8*)(bB);
        short8 b1 = *(const short8*)(bB + 32);
        short8 b2 = *(const short8*)(bB + 64);
        short8 b3 = *(const short8*)(bB + 96);
        acc = __builtin_amdgcn_mfma_f32_16x16x32_bf16(a0, b0, acc, 0, 0, 0);
        acc = __builtin_amdgcn_mfma_f32_16x16x32_bf16(a1, b1, acc, 0, 0, 0);
        acc = __builtin_amdgcn_mfma_f32_16x16x32_bf16(a2, b2, acc, 0, 0, 0);
        acc = __builtin_amdgcn_mfma_f32_16x16x32_bf16(a3, b3, acc, 0, 0, 0);
#pragma unroll
        for (int r = 0; r < 4; r++) {
            long row = base + w * 16 + q * 4 + r;
            if (row < NN) Z[(row << 7) + col] = f2b(fmaxf(acc[r], 0.f));
        }
    }
}

// ---- GraphNorm + relu (bf16 in-place)
__global__ __launch_bounds__(512) void k_gnorm(ushort_t* __restrict__ H, const int* __restrict__ goff,
                                               const float* __restrict__ scale,
                                               const float* __restrict__ weight,
                                               const float* __restrict__ bias) {
    int g = blockIdx.x;
    int s = goff[g], e = goff[g + 1];
    float cnt = (float)max(e - s, 1);
    int f = threadIdx.x & 127;
    int r = threadIdx.x >> 7;
    float sum = 0.f, sumsq = 0.f;
    for (int i = s + r; i < e; i += 4) {
        float v = b2f(H[(long)i * HIDD + f]);
        sum += v; sumsq += v * v;
    }
    __shared__ float red[2][4][128];
    red[0][r][f] = sum; red[1][r][f] = sumsq;
    __syncthreads();
    if (r == 0) {
        sum = red[0][0][f] + red[0][1][f] + red[0][2][f] + red[0][3][f];
        sumsq = red[1][0][f] + red[1][1][f] + red[1][2][f] + red[1][3][f];
        float mean = sum / cnt;
        float ms = mean * scale[f];
        float var = sumsq / cnt - 2.f * ms * mean + ms * ms;
        float inv = weight[f] / sqrtf(var + 1e-8f);
        red[0][0][f] = ms; red[1][0][f] = inv;
    }
    __syncthreads();
    float ms = red[0][0][f], inv = red[1][0][f];
    float b = bias[f];
    for (int i = s + r; i < e; i += 4) {
        long idx = (long)i * HIDD + f;
        float v = (b2f(H[idx]) - ms) * inv + b;
        H[idx] = f2b(v > 0.f ? v : 0.f);
    }
}

// ---- per-graph pooling of bf16 Z -> pooled fp32 [G,128]
__global__ __launch_bounds__(512) void k_pool(const ushort_t* __restrict__ Z, const int* __restrict__ goff,
                                              float* __restrict__ pooled) {
    int g = blockIdx.x;
    int s = goff[g], e = goff[g + 1];
    int f = threadIdx.x & 127;
    int r = threadIdx.x >> 7;
    float sum = 0.f;
    for (int i = s + r; i < e; i += 4) sum += b2f(Z[(long)i * HIDD + f]);
    __shared__ float red[4][128];
    red[r][f] = sum;
    __syncthreads();
    if (r == 0) pooled[g * HIDD + f] = red[0][f] + red[1][f] + red[2][f] + red[3][f];
}

// ---- out[g, l*64+t] = pooled[g] @ pw2 + count*pb2  (fp32)
__global__ __launch_bounds__(64) void k_out(const float* __restrict__ pooled, const int* __restrict__ goff,
                                            const float* __restrict__ W, const float* __restrict__ B,
                                            float* __restrict__ out, int l) {
    int g = blockIdx.x;
    int t = threadIdx.x;
    __shared__ float p[128];
    p[t] = pooled[g * HIDD + t];
    p[t + 64] = pooled[g * HIDD + 64 + t];
    __syncthreads();
    float cnt = (float)(goff[g + 1] - goff[g]);
    float acc = cnt * B[t];
    for (int k = 0; k < HIDD; k++) acc += p[k] * W[k * TGTT + t];
    out[(long)g * (3 * TGTT) + l * TGTT + t] = acc;
}

extern "C" void kernel_launch(void* const* d_in, const int* in_sizes, int n_in,
                              void* d_out, int out_size, void* d_ws, size_t ws_size,
                              hipStream_t stream) {
    const float* x    = (const float*)d_in[0];
    const int*   ei   = (const int*)d_in[1];
    const int*   batch= (const int*)d_in[2];
    const float* cw1  = (const float*)d_in[3];
    const float* cb1  = (const float*)d_in[4];
    const float* cw2  = (const float*)d_in[5];
    const float* cb2  = (const float*)d_in[6];
    const float* eps  = (const float*)d_in[7];
    const float* gsc  = (const float*)d_in[8];
    const float* gw   = (const float*)d_in[9];
    const float* gb   = (const float*)d_in[10];
    const float* pw1  = (const float*)d_in[11];
    const float* pb1  = (const float*)d_in[12];
    const float* pw2  = (const float*)d_in[13];
    const float* pb2  = (const float*)d_in[14];
    float* out = (float*)d_out;

    ushort_t* Xb = (ushort_t*)d_ws;                       // N*128 bf16
    ushort_t* A  = Xb + (size_t)NN * HIDD;                // N*128 bf16 (also Z)
    ushort_t* H  = A + (size_t)NN * HIDD;                 // N*128 bf16
    ushort_t* Wt = H + (size_t)NN * HIDD;                 // 9*128*128 bf16
    float* pooled = (float*)(Wt + (size_t)9 * HIDD * HIDD); // G*128 f32
    int* goff   = (int*)(pooled + (size_t)GGG * HIDD);    // G+1
    int* rowptr = goff + (GGG + 1);                       // N+1
    int* deg    = rowptr + (NN + 1);                      // N
    int* cursor = deg + NN;                               // N
    int* bsum   = cursor + NN;                            // NSB
    int* csr    = bsum + NSB;                             // E

    k_goff<<<3, 256, 0, stream>>>(batch, goff);
    k_cvt<<<(int)(((long)NN * 32 + 255) / 256), 256, 0, stream>>>(x, Xb);
    k_prep<<<9, 256, 0, stream>>>(cw1, cw2, pw1, Wt);

    hipMemsetAsync(deg, 0, (size_t)(2 * NN) * sizeof(int), stream);
    k_count<<<(EE + 255) / 256, 256, 0, stream>>>(ei, deg);
    k_bsum<<<NSB, SCANB, 0, stream>>>(deg, bsum);
    k_bscan<<<1, 64, 0, stream>>>(bsum, rowptr);
    k_scan<<<NSB, SCANB, 0, stream>>>(deg, bsum, rowptr);
    k_fill<<<(EE + 255) / 256, 256, 0, stream>>>(ei, rowptr, cursor, csr);

    for (int l = 0; l < 3; l++) {
        const ushort_t* hin = (l == 0) ? Xb : H;
        ushort_t* Wt1 = Wt + (size_t)(l * 3 + 0) * HIDD * HIDD;
        ushort_t* Wt2 = Wt + (size_t)(l * 3 + 1) * HIDD * HIDD;
        ushort_t* Wtp = Wt + (size_t)(l * 3 + 2) * HIDD * HIDD;
        k_gather<<<(NN + 15) / 16, 256, 0, stream>>>(hin, rowptr, csr, eps, l, A);
        k_mlp2<<<(NN + 63) / 64, 256, 0, stream>>>(A, Wt1, cb1 + l * HIDD, Wt2, cb2 + l * HIDD, H);
        k_gnorm<<<GGG, 512, 0, stream>>>(H, goff, gsc + l * HIDD, gw + l * HIDD, gb + l * HIDD);
        k_gemm_relu<<<(NN + 63) / 64, 256, 0, stream>>>(H, Wtp, pb1 + l * HIDD, A);
        k_pool<<<GGG, 512, 0, stream>>>(A, goff, pooled);
        k_out<<<GGG, 64, 0, stream>>>(pooled, goff, pw2 + (size_t)l * HIDD * TGTT, pb2 + l * TGTT, out, l);
    }
}